// Round 15
// baseline (304.497 us; speedup 1.0000x reference)
//
#include <hip/hip_runtime.h>
#include <hip/hip_cooperative_groups.h>

namespace cg = cooperative_groups;

#define N_NODES 32768
#define N_EDGES 65536

typedef float f32x4 __attribute__((ext_vector_type(4)));
typedef float f32x2 __attribute__((ext_vector_type(2)));
typedef short s16x8 __attribute__((ext_vector_type(8)));

__device__ __forceinline__ unsigned short f2bf(float f){
  unsigned u = __float_as_uint(f);
  u += 0x7FFFu + ((u >> 16) & 1u);          // round-to-nearest-even
  return (unsigned short)(u >> 16);
}
__device__ __forceinline__ float bf2f(unsigned short b){
  return __uint_as_float(((unsigned)b) << 16);
}

// ======= fused setup (cooperative): prep + zero + hist + scanA + scanB + fill =======
// blocks 0..128   : W2f slab transpose via LDS (e2_w2 / e2_b2 -> MFMA A-fragment order)
// blocks 129..192 : T1g (e1_w2 fragments)
// blocks 193..448 : zero cnti|cur -> S1 -> hist -> S2 -> scanA (193..320) -> S3
//                   -> local scanB of bsum + fill (block 193 publishes bsx)
// All branches execute exactly 3 grid.sync()s.
__global__ void k_setup(const float* __restrict__ e2_w2, const float* __restrict__ e2_b2,
                        const float* __restrict__ e1_w2,
                        unsigned short* __restrict__ W2f, unsigned short* __restrict__ T1g,
                        const int* __restrict__ ei, int* __restrict__ cz /*cnti|cur*/,
                        int* __restrict__ cur,
                        int* __restrict__ lex, int* __restrict__ bsx,
                        int* __restrict__ bsum, int* __restrict__ eslot)
{
  cg::grid_group grid = cg::this_grid();
  __shared__ float S[4096];
  __shared__ int sb[136];     // [0..127] fill-scan; [128..131] scanA wsum; [132] fill w0
  const int b = blockIdx.x, tid = threadIdx.x;

  if (b < 129){
    const float* src = (b < 128) ? (e2_w2 + b * 4096) : e2_b2;
    #pragma unroll
    for (int t = 0; t < 4096; t += 256) S[t + tid] = src[t + tid];
    __syncthreads();
    grid.sync();                                   // S1
    #pragma unroll
    for (int t = 0; t < 4096; t += 256){
      int u = t + tid;
      int j = u & 7, l = (u >> 3) & 63, half = (u >> 9) & 1, ot = (u >> 10) & 3;
      int i = half * 32 + ((l >> 4) << 3) + j;
      int o = ot * 16 + (l & 15);
      W2f[b * 4096 + u] = f2bf(S[i * 64 + o]);
    }
    grid.sync();                                   // S2
    grid.sync();                                   // S3
  } else if (b < 193){
    int t = (b - 129) * 256 + tid;                 // t < 16384
    int j = t & 7, l = (t >> 3) & 63, half = (t >> 9) & 1, ot = (t >> 10) & 3, i = t >> 12;
    int kf = half * 32 + ((l >> 4) << 3) + j;
    int o = ot * 16 + (l & 15);
    T1g[t] = f2bf(e1_w2[kf * 256 + i * 64 + o]);
    grid.sync();                                   // S1
    grid.sync();                                   // S2
    grid.sync();                                   // S3
  } else {
    const int idx = (b - 193) * 256 + tid;         // 0..65535
    cz[idx] = 0;                                   // zero cnti + cur (contiguous)
    grid.sync();                                   // S1
    const int d = ei[N_EDGES + idx];
    atomicAdd(cz + d, 1);                          // degree histogram into cnti
    grid.sync();                                   // S2
    if (b < 321){                                  // scanA: 128 node blocks
      int n = idx;                                 // < 32768
      int c = cz[n];
      int v = c;
      int lane = tid & 63;
      #pragma unroll
      for (int dd = 1; dd < 64; dd <<= 1){
        int t2 = __shfl_up(v, dd);
        if (lane >= dd) v += t2;
      }
      if (lane == 63) sb[128 + (tid >> 6)] = v;
      __syncthreads();
      int off = 0;
      for (int i = 0; i < (tid >> 6); ++i) off += sb[128 + i];
      lex[n] = off + v - c;
      if (tid == 255) bsum[b - 193] = off + v;
    }
    grid.sync();                                   // S3
    // local scanB of the 128 block sums, then fill
    if (tid < 128) sb[tid] = bsum[tid];
    __syncthreads();
    int c128 = (tid < 128) ? sb[tid] : 0;
    int v = c128;
    int lane = tid & 63;
    #pragma unroll
    for (int dd = 1; dd < 64; dd <<= 1){
      int t2 = __shfl_up(v, dd);
      if (lane >= dd) v += t2;
    }
    if (tid == 63) sb[132] = v;
    __syncthreads();
    if (tid < 128) sb[tid] = v + ((tid >= 64) ? sb[132] : 0) - c128;  // exclusive scan
    __syncthreads();
    if (b == 193 && tid < 128) bsx[tid] = sb[tid]; // publish for node kernels
    int base = lex[d] + sb[d >> 8];
    eslot[idx] = base + atomicAdd(cur + d, 1);
  }
}

// ---------------- layer-1 edge messages: 4 waves, ot-split, 4 i-GEMMs, bf16 CSR store ----------------
__launch_bounds__(256, 4)
__global__ void k_msg1(const float* __restrict__ x, const float* __restrict__ ea,
                       const int* __restrict__ ei, const int* __restrict__ eslot,
                       const float* __restrict__ e1_w1, const float* __restrict__ e1_b1,
                       const float* __restrict__ e1_b2,
                       const unsigned short* __restrict__ T1g,
                       unsigned short* __restrict__ msg1b)
{
  __shared__ float eas[64 * 4];
  __shared__ unsigned short F1f[8 * 64 * 8];   // B-fragment layout [(et*2+half)][lane][8]
  const int tid = threadIdx.x;
  const int eblk = blockIdx.x * 64;

  if (tid < 64) ((float4*)eas)[tid] = ((const float4*)ea)[eblk + tid];
  __syncthreads();
  { // F1 = relu(ea @ e1_w1 + b1), stored directly in B-fragment order
    int kf = tid & 63, eh = tid >> 6;
    float w0 = e1_w1[kf], w1 = e1_w1[64 + kf], w2 = e1_w1[128 + kf], w3 = e1_w1[192 + kf];
    float bb = e1_b1[kf];
    int half = kf >> 5, hi = (kf >> 3) & 3, j = kf & 7;
    for (int e = eh * 16; e < eh * 16 + 16; ++e){
      float s = fmaf(eas[e*4+0], w0, fmaf(eas[e*4+1], w1, fmaf(eas[e*4+2], w2, fmaf(eas[e*4+3], w3, bb))));
      F1f[(((e >> 4) * 2 + half) * 64 + hi * 16 + (e & 15)) * 8 + j] = f2bf(fmaxf(s, 0.f));
    }
  }
  __syncthreads();

  const int l = tid & 63, lm = l & 15, lg = l >> 4;
  const int ot = tid >> 6;
  int esl[4];
  float xs[4][4];
  s16x8 bf[4][2];
  #pragma unroll
  for (int et = 0; et < 4; ++et){
    int e = eblk + et * 16 + lm;
    int s = ei[e];
    esl[et] = eslot[e];
    float4 xv = *(const float4*)(x + s * 4);
    xs[et][0] = xv.x; xs[et][1] = xv.y; xs[et][2] = xv.z; xs[et][3] = xv.w;
    bf[et][0] = ((const s16x8*)F1f)[(et * 2 + 0) * 64 + l];
    bf[et][1] = ((const s16x8*)F1f)[(et * 2 + 1) * 64 + l];
  }
  f32x4 acc[4];
  #pragma unroll
  for (int et = 0; et < 4; ++et) acc[et] = (f32x4){0.f, 0.f, 0.f, 0.f};

  #pragma unroll
  for (int i = 0; i < 4; ++i){
    const s16x8* p = (const s16x8*)(T1g + (i * 4 + ot) * 1024);
    s16x8 a0 = p[l], a1 = p[64 + l];
    #pragma unroll
    for (int et = 0; et < 4; ++et){
      f32x4 g = (f32x4){0.f, 0.f, 0.f, 0.f};
      g = __builtin_amdgcn_mfma_f32_16x16x32_bf16(a0, bf[et][0], g, 0, 0, 0);
      g = __builtin_amdgcn_mfma_f32_16x16x32_bf16(a1, bf[et][1], g, 0, 0, 0);
      acc[et] += xs[et][i] * g;
    }
  }
  // bias fold: acc[et][r] += sum_i xs[et][i] * e1_b2[i*64 + o],  o = ot*16 + lg*4 + r
  float b2v[4][4];
  #pragma unroll
  for (int i = 0; i < 4; ++i)
    #pragma unroll
    for (int r = 0; r < 4; ++r) b2v[i][r] = e1_b2[i * 64 + ot * 16 + lg * 4 + r];
  #pragma unroll
  for (int et = 0; et < 4; ++et)
    #pragma unroll
    for (int r = 0; r < 4; ++r)
      #pragma unroll
      for (int i = 0; i < 4; ++i) acc[et][r] = fmaf(xs[et][i], b2v[i][r], acc[et][r]);

  #pragma unroll
  for (int et = 0; et < 4; ++et){
    unsigned p0 = ((unsigned)f2bf(acc[et][1]) << 16) | f2bf(acc[et][0]);
    unsigned p1 = ((unsigned)f2bf(acc[et][3]) << 16) | f2bf(acc[et][2]);
    *(uint2*)(msg1b + (size_t)esl[et] * 64 + ot * 16 + lg * 4) = make_uint2(p0, p1);
  }
}

// ---------------- node update 1: contiguous CSR gather-mean + root + LN -> h1b ----------------
__launch_bounds__(256)
__global__ void k_node1(const float* __restrict__ x, const float* __restrict__ root1,
                        const float* __restrict__ bias1, const float* __restrict__ lng,
                        const float* __restrict__ lnb, const int* __restrict__ cnti,
                        const int* __restrict__ lex, const int* __restrict__ bsx,
                        const unsigned short* __restrict__ msg1b, unsigned short* __restrict__ h1b)
{
  const int tid = threadIdx.x;
  int n = blockIdx.x * 4 + (tid >> 6);
  int o = tid & 63;
  int rp = lex[n] + bsx[n >> 8];
  int deg = cnti[n];
  float s = 0.f;
  for (int j = 0; j < deg; ++j) s += bf2f(msg1b[(size_t)(rp + j) * 64 + o]);
  float v = s * (1.f / fmaxf((float)deg, 1.f));
  float4 xv = *(const float4*)(x + n * 4);
  v = fmaf(xv.x, root1[o], v);
  v = fmaf(xv.y, root1[64 + o], v);
  v = fmaf(xv.z, root1[128 + o], v);
  v = fmaf(xv.w, root1[192 + o], v);
  v = fmaxf(v + bias1[o], 0.f);
  float m = v;
  #pragma unroll
  for (int d = 32; d > 0; d >>= 1) m += __shfl_xor(m, d);
  m *= (1.f / 64.f);
  float dd = v - m;
  float var = dd * dd;
  #pragma unroll
  for (int d = 32; d > 0; d >>= 1) var += __shfl_xor(var, d);
  var *= (1.f / 64.f);
  float out = dd * rsqrtf(var + 1e-5f) * lng[o] + lnb[o];
  h1b[n * 64 + o] = f2bf(out);
}

// ---------------- layer-2 edge messages: 8 waves (ot x eh), f32 F2s, pk-fma scale, asm prefetch ----------------
__launch_bounds__(512, 4)
__global__ void k_msg2(const float* __restrict__ ea, const int* __restrict__ ei,
                       const int* __restrict__ eslot,
                       const float* __restrict__ e2_w1, const float* __restrict__ e2_b1,
                       const unsigned short* __restrict__ h1b,
                       const unsigned short* __restrict__ W2f,
                       float* __restrict__ msg)
{
  __shared__ float eas[128 * 4];
  __shared__ float F2s[128 * 132];   // f32 scales, padded row
  const int tid = threadIdx.x;
  const int eblk = blockIdx.x * 128;
  const int w = tid >> 6, l = tid & 63, lm = l & 15, lg = l >> 4;
  const int ot = w >> 1, eh = w & 1;

  // early scattered loads: issue before the F2 phase so HBM/L2 latency hides under it
  int esl[4];
  s16x8 bh[4][2];
  #pragma unroll
  for (int et = 0; et < 4; ++et){
    int eloc = eh * 64 + et * 16 + lm;
    int e = eblk + eloc;
    int s = ei[e];
    esl[et] = eslot[e];
    const s16x8* hp = (const s16x8*)(h1b + s * 64);
    bh[et][0] = hp[lg];
    bh[et][1] = hp[4 + lg];
  }

  if (tid < 128) ((float4*)eas)[tid] = ((const float4*)ea)[eblk + tid];
  __syncthreads();
  {
    int kf = tid & 127, q = tid >> 7;   // q in 0..3, 32 edges each
    float w0 = e2_w1[kf], w1 = e2_w1[128 + kf], w2 = e2_w1[256 + kf], w3 = e2_w1[384 + kf];
    float bb = e2_b1[kf];
    for (int e = q * 32; e < q * 32 + 32; ++e){
      float s = fmaf(eas[e*4+0], w0, fmaf(eas[e*4+1], w1, fmaf(eas[e*4+2], w2, fmaf(eas[e*4+3], w3, bb))));
      F2s[e * 132 + kf] = fmaxf(s, 0.f);
    }
  }
  __syncthreads();

  f32x2 accL[4], accH[4];
  #pragma unroll
  for (int et = 0; et < 4; ++et){ accL[et] = (f32x2){0.f, 0.f}; accH[et] = (f32x2){0.f, 0.f}; }

  const int voff = ot * 2048 + l * 16;   // byte offset of this lane's fragment within a slab
  s16x8 A0[2], A1[2], A2[2], A3[2];

  // asm loads: compiler cannot sink these to their use; counted vmcnt enforces depth-4 pipeline.
  // NOTE: requires no spilling of A0..A3 (in-flight asm loads) — keep VGPR cap at 128 (512,4).
#define LOADA(DST, KF) { \
    const unsigned short* sb = W2f + (size_t)(KF) * 4096; \
    asm volatile("global_load_dwordx4 %0, %2, %3\n\t" \
                 "global_load_dwordx4 %1, %2, %3 offset:1024" \
      : "=&v"(DST[0]), "=&v"(DST[1]) : "v"(voff), "s"(sb)); }
#define WAITA(N) do { asm volatile("s_waitcnt vmcnt(" #N ")"); \
                      __builtin_amdgcn_sched_barrier(0); } while(0);
#define STEP(A, J) { \
    __builtin_amdgcn_s_setprio(1); \
    _Pragma("unroll") \
    for (int et = 0; et < 4; ++et){ \
      f32x4 g = (f32x4){0.f, 0.f, 0.f, 0.f}; \
      g = __builtin_amdgcn_mfma_f32_16x16x32_bf16(A[0], bh[et][0], g, 0, 0, 0); \
      g = __builtin_amdgcn_mfma_f32_16x16x32_bf16(A[1], bh[et][1], g, 0, 0, 0); \
      float fs = f2c[et][J]; \
      f32x2 ff = (f32x2){fs, fs}; \
      f32x2 glo = __builtin_shufflevector(g, g, 0, 1); \
      f32x2 ghi = __builtin_shufflevector(g, g, 2, 3); \
      accL[et] = __builtin_elementwise_fma(glo, ff, accL[et]); \
      accH[et] = __builtin_elementwise_fma(ghi, ff, accH[et]); \
    } \
    __builtin_amdgcn_s_setprio(0); }

  LOADA(A0, 0)
  LOADA(A1, 1)
  LOADA(A2, 2)
  LOADA(A3, 3)
  #pragma unroll 1
  for (int kf = 0; kf < 128; kf += 4){
    f32x4 f2c[4];
    #pragma unroll
    for (int et = 0; et < 4; ++et)
      f2c[et] = *(const f32x4*)&F2s[(eh * 64 + et * 16 + lm) * 132 + kf];
    const int k5 = (kf + 5 > 128) ? 128 : kf + 5;
    const int k6 = (kf + 6 > 128) ? 128 : kf + 6;
    const int k7 = (kf + 7 > 128) ? 128 : kf + 7;
    WAITA(6) STEP(A0, 0) LOADA(A0, kf + 4)   // kf+4 <= 128 always
    WAITA(6) STEP(A1, 1) LOADA(A1, k5)
    WAITA(6) STEP(A2, 2) LOADA(A2, k6)
    WAITA(6) STEP(A3, 3) LOADA(A3, k7)
  }
  WAITA(0)
  // kf = 128: bias slab (f2 == 1) now in A0, accumulate directly
  #pragma unroll
  for (int et = 0; et < 4; ++et){
    f32x4 g = (f32x4){0.f, 0.f, 0.f, 0.f};
    g = __builtin_amdgcn_mfma_f32_16x16x32_bf16(A0[0], bh[et][0], g, 0, 0, 0);
    g = __builtin_amdgcn_mfma_f32_16x16x32_bf16(A0[1], bh[et][1], g, 0, 0, 0);
    accL[et] += __builtin_shufflevector(g, g, 0, 1);
    accH[et] += __builtin_shufflevector(g, g, 2, 3);
  }
#undef LOADA
#undef WAITA
#undef STEP

  #pragma unroll
  for (int et = 0; et < 4; ++et){
    f32x4 o4;
    o4[0] = accL[et][0]; o4[1] = accL[et][1];
    o4[2] = accH[et][0]; o4[3] = accH[et][1];
    *(f32x4*)(msg + (size_t)esl[et] * 64 + ot * 16 + lg * 4) = o4;
  }
}

// ---------------- node update 2: gather-mean + h1@root2 + LN, 64 nodes/block partials ----------------
__launch_bounds__(1024)
__global__ void k_node2(const unsigned short* __restrict__ h1b, const float* __restrict__ root2,
                        const float* __restrict__ bias2, const float* __restrict__ lng,
                        const float* __restrict__ lnb, const int* __restrict__ cnti,
                        const int* __restrict__ lex, const int* __restrict__ bsx,
                        const float* __restrict__ msg, float* __restrict__ partial)
{
  const int tid = threadIdx.x;
  const int q = tid >> 6, o = tid & 63;
  float tsum = 0.f;
  #pragma unroll 1
  for (int it = 0; it < 4; ++it){
    int n = blockIdx.x * 64 + it * 16 + q;
    int rp = lex[n] + bsx[n >> 8];
    int deg = cnti[n];
    float s = 0.f;
    for (int j = 0; j < deg; ++j) s += msg[(size_t)(rp + j) * 64 + o];
    float v = s * (1.f / fmaxf((float)deg, 1.f));
    const s16x8* hp = (const s16x8*)(h1b + n * 64);
    #pragma unroll
    for (int c = 0; c < 8; ++c){
      s16x8 hv = hp[c];
      #pragma unroll
      for (int j = 0; j < 8; ++j)
        v = fmaf(bf2f((unsigned short)hv[j]), root2[(c * 8 + j) * 64 + o], v);
    }
    v = fmaxf(v + bias2[o], 0.f);
    float m = v;
    #pragma unroll
    for (int d = 32; d > 0; d >>= 1) m += __shfl_xor(m, d);
    m *= (1.f / 64.f);
    float dd = v - m;
    float var = dd * dd;
    #pragma unroll
    for (int d = 32; d > 0; d >>= 1) var += __shfl_xor(var, d);
    var *= (1.f / 64.f);
    tsum += dd * rsqrtf(var + 1e-5f) * lng[o] + lnb[o];
  }
  __shared__ float pp[16][64];
  pp[q][o] = tsum;
  __syncthreads();
  if (tid < 64){
    float t = 0.f;
    #pragma unroll
    for (int k = 0; k < 16; ++k) t += pp[k][tid];
    partial[blockIdx.x * 64 + tid] = t;
  }
}

// ---------------- final reduce: 512 partial rows -> 64 outputs ----------------
__launch_bounds__(1024)
__global__ void k_out(const float* __restrict__ partial, float* __restrict__ out){
  const int tid = threadIdx.x;
  int o = tid & 63, q = tid >> 6;      // q in 0..15
  float s = 0.f;
  for (int b = q; b < 512; b += 16) s += partial[b * 64 + o];
  __shared__ float pp[16][64];
  pp[q][o] = s;
  __syncthreads();
  if (tid < 64){
    float t = 0.f;
    #pragma unroll
    for (int k = 0; k < 16; ++k) t += pp[k][tid];
    out[tid] = t * (1.f / 32768.f);
  }
}

extern "C" void kernel_launch(void* const* d_in, const int* in_sizes, int n_in,
                              void* d_out, int out_size, void* d_ws, size_t ws_size,
                              hipStream_t stream)
{
  const float* x      = (const float*)d_in[0];
  const float* ea     = (const float*)d_in[1];
  const int*   ei     = (const int*)  d_in[2];
  const float* e1_w1  = (const float*)d_in[4];
  const float* e1_b1  = (const float*)d_in[5];
  const float* e1_w2  = (const float*)d_in[6];
  const float* e1_b2  = (const float*)d_in[7];
  const float* root1  = (const float*)d_in[8];
  const float* bias1  = (const float*)d_in[9];
  const float* ln1g   = (const float*)d_in[10];
  const float* ln1b   = (const float*)d_in[11];
  const float* e2_w1  = (const float*)d_in[12];
  const float* e2_b1  = (const float*)d_in[13];
  const float* e2_w2  = (const float*)d_in[14];
  const float* e2_b2  = (const float*)d_in[15];
  const float* root2  = (const float*)d_in[16];
  const float* bias2  = (const float*)d_in[17];
  const float* ln2g   = (const float*)d_in[18];
  const float* ln2b   = (const float*)d_in[19];

  char* w = (char*)d_ws;
  float*          msg     = (float*)(w);                       // 16,777,216 B (f32, layer 2)
  unsigned short* msg1b   = (unsigned short*)(w);              //  8,388,608 B (bf16, layer 1 — overlaid)
  unsigned short* h1b     = (unsigned short*)(w + 16777216);   //  4,194,304 B
  unsigned short* W2f     = (unsigned short*)(w + 20971520);   //  1,056,768 B
  unsigned short* T1g     = (unsigned short*)(w + 22028288);   //     32,768 B
  int*            cnti    = (int*)(w + 22061056);              //    131,072 B  (zeroed in k_setup)
  int*            cur     = (int*)(w + 22192128);              //    131,072 B  (zeroed in k_setup)
  int*            lex     = (int*)(w + 22323200);              //    131,072 B
  int*            bsx     = (int*)(w + 22454272);              //        512 B
  int*            bsum    = (int*)(w + 22454784);              //        512 B
  int*            eslot   = (int*)(w + 22455296);              //    262,144 B
  float*          partial = (float*)(w + 22717440);            //    131,072 B

  {
    const float* a0 = e2_w2; const float* a1 = e2_b2; const float* a2 = e1_w2;
    unsigned short* a3 = W2f; unsigned short* a4 = T1g;
    const int* a5 = ei; int* a6 = cnti; int* a7 = cur;
    int* a8 = lex; int* a9 = bsx; int* a10 = bsum; int* a11 = eslot;
    void* args[] = {&a0, &a1, &a2, &a3, &a4, &a5, &a6, &a7, &a8, &a9, &a10, &a11};
    hipLaunchCooperativeKernel(reinterpret_cast<void*>(k_setup), dim3(449), dim3(256),
                               args, 0, stream);
  }
  k_msg1 <<<1024, 256, 0, stream>>>(x, ea, ei, eslot, e1_w1, e1_b1, e1_b2, T1g, msg1b);
  k_node1<<<8192, 256, 0, stream>>>(x, root1, bias1, ln1g, ln1b, cnti, lex, bsx, msg1b, h1b);
  k_msg2 <<<512, 512, 0, stream>>>(ea, ei, eslot, e2_w1, e2_b1, h1b, W2f, msg);
  k_node2<<<512, 1024, 0, stream>>>(h1b, root2, bias2, ln2g, ln2b, cnti, lex, bsx, msg, partial);
  k_out  <<<1, 1024, 0, stream>>>(partial, (float*)d_out);
}

// Round 16
// 151.756 us; speedup vs baseline: 2.0065x; 2.0065x over previous
//
#include <hip/hip_runtime.h>

#define N_NODES 32768
#define N_EDGES 65536

typedef float f32x4 __attribute__((ext_vector_type(4)));
typedef float f32x2 __attribute__((ext_vector_type(2)));
typedef short s16x8 __attribute__((ext_vector_type(8)));

__device__ __forceinline__ unsigned short f2bf(float f){
  unsigned u = __float_as_uint(f);
  u += 0x7FFFu + ((u >> 16) & 1u);          // round-to-nearest-even
  return (unsigned short)(u >> 16);
}
__device__ __forceinline__ float bf2f(unsigned short b){
  return __uint_as_float(((unsigned)b) << 16);
}

// ---- prep (coalesced): blocks 0..128  -> W2f slab transpose via LDS
// ----                   blocks 129..192 -> T1g (e1_w2 fragments, small)
// ----                   blocks 193..448 -> zero cnti|cur (65536 ints)
__global__ void k_prep(const float* __restrict__ e2_w2, const float* __restrict__ e2_b2,
                       const float* __restrict__ e1_w2,
                       unsigned short* __restrict__ W2f, unsigned short* __restrict__ T1g,
                       int* __restrict__ cz){
  __shared__ float S[4096];
  const int b = blockIdx.x, tid = threadIdx.x;
  if (b < 129){
    const float* src = (b < 128) ? (e2_w2 + b * 4096) : e2_b2;
    #pragma unroll
    for (int t = 0; t < 4096; t += 256) S[t + tid] = src[t + tid];
    __syncthreads();
    #pragma unroll
    for (int t = 0; t < 4096; t += 256){
      int u = t + tid;
      int j = u & 7, l = (u >> 3) & 63, half = (u >> 9) & 1, ot = (u >> 10) & 3;
      int i = half * 32 + ((l >> 4) << 3) + j;
      int o = ot * 16 + (l & 15);
      W2f[b * 4096 + u] = f2bf(S[i * 64 + o]);
    }
  } else if (b < 193){
    int t = (b - 129) * 256 + tid;      // t < 16384
    int j = t & 7, l = (t >> 3) & 63, half = (t >> 9) & 1, ot = (t >> 10) & 3, i = t >> 12;
    int kf = half * 32 + ((l >> 4) << 3) + j;
    int o = ot * 16 + (l & 15);
    T1g[t] = f2bf(e1_w2[kf * 256 + i * 64 + o]);
  } else {
    int z = (b - 193) * 256 + tid;
    if (z < 65536) cz[z] = 0;
  }
}

// ---------------- degree histogram (int) ----------------
__global__ void k_hist(const int* __restrict__ ei, int* __restrict__ cnti){
  int i = blockIdx.x * 256 + threadIdx.x;
  if (i < N_EDGES) atomicAdd(cnti + ei[N_EDGES + i], 1);
}

// ---------------- scan level A: per-256-node block exclusive scan + block sums ----------------
__global__ void k_scanA(const int* __restrict__ cnti, int* __restrict__ lex, int* __restrict__ bsum){
  const int tid = threadIdx.x;
  int n = blockIdx.x * 256 + tid;
  int c = cnti[n];
  int v = c;
  int lane = tid & 63;
  #pragma unroll
  for (int d = 1; d < 64; d <<= 1){
    int t = __shfl_up(v, d);
    if (lane >= d) v += t;
  }
  __shared__ int wsum[4];
  if (lane == 63) wsum[tid >> 6] = v;
  __syncthreads();
  int off = 0;
  for (int i = 0; i < (tid >> 6); ++i) off += wsum[i];
  lex[n] = off + v - c;
  if (tid == 255) bsum[blockIdx.x] = off + v;
}

// ---------------- per-edge CSR slot assignment (scanB folded in: local scan of bsum) ----------------
__global__ void k_fill(const int* __restrict__ ei, const int* __restrict__ lex,
                       const int* __restrict__ bsum, int* __restrict__ cur,
                       int* __restrict__ eslot, int* __restrict__ bsx){
  __shared__ int sb[128];
  __shared__ int w0s;
  const int tid = threadIdx.x;
  const int lane = tid & 63;
  int c = 0, v = 0;
  if (tid < 128){               // waves 0,1 fully active (wave-uniform branch)
    c = bsum[tid];
    v = c;
    #pragma unroll
    for (int d = 1; d < 64; d <<= 1){
      int t = __shfl_up(v, d);
      if (lane >= d) v += t;
    }
  }
  if (tid == 63) w0s = v;
  __syncthreads();
  if (tid < 128) sb[tid] = v + ((tid >= 64) ? w0s : 0) - c;   // exclusive scan of bsum
  __syncthreads();
  if (blockIdx.x == 0 && tid < 128) bsx[tid] = sb[tid];       // publish for node kernels
  int e = blockIdx.x * 256 + tid;
  int d = ei[N_EDGES + e];
  int base = lex[d] + sb[d >> 8];
  eslot[e] = base + atomicAdd(cur + d, 1);
}

// ---------------- layer-1 edge messages: 4 waves, ot-split, 4 i-GEMMs, bf16 CSR store ----------------
__launch_bounds__(256, 4)
__global__ void k_msg1(const float* __restrict__ x, const float* __restrict__ ea,
                       const int* __restrict__ ei, const int* __restrict__ eslot,
                       const float* __restrict__ e1_w1, const float* __restrict__ e1_b1,
                       const float* __restrict__ e1_b2,
                       const unsigned short* __restrict__ T1g,
                       unsigned short* __restrict__ msg1b)
{
  __shared__ float eas[64 * 4];
  __shared__ unsigned short F1f[8 * 64 * 8];   // B-fragment layout [(et*2+half)][lane][8]
  const int tid = threadIdx.x;
  const int eblk = blockIdx.x * 64;

  if (tid < 64) ((float4*)eas)[tid] = ((const float4*)ea)[eblk + tid];
  __syncthreads();
  { // F1 = relu(ea @ e1_w1 + b1), stored directly in B-fragment order
    int kf = tid & 63, eh = tid >> 6;
    float w0 = e1_w1[kf], w1 = e1_w1[64 + kf], w2 = e1_w1[128 + kf], w3 = e1_w1[192 + kf];
    float bb = e1_b1[kf];
    int half = kf >> 5, hi = (kf >> 3) & 3, j = kf & 7;
    for (int e = eh * 16; e < eh * 16 + 16; ++e){
      float s = fmaf(eas[e*4+0], w0, fmaf(eas[e*4+1], w1, fmaf(eas[e*4+2], w2, fmaf(eas[e*4+3], w3, bb))));
      F1f[(((e >> 4) * 2 + half) * 64 + hi * 16 + (e & 15)) * 8 + j] = f2bf(fmaxf(s, 0.f));
    }
  }
  __syncthreads();

  const int l = tid & 63, lm = l & 15, lg = l >> 4;
  const int ot = tid >> 6;
  int esl[4];
  float xs[4][4];
  s16x8 bf[4][2];
  #pragma unroll
  for (int et = 0; et < 4; ++et){
    int e = eblk + et * 16 + lm;
    int s = ei[e];
    esl[et] = eslot[e];
    float4 xv = *(const float4*)(x + s * 4);
    xs[et][0] = xv.x; xs[et][1] = xv.y; xs[et][2] = xv.z; xs[et][3] = xv.w;
    bf[et][0] = ((const s16x8*)F1f)[(et * 2 + 0) * 64 + l];
    bf[et][1] = ((const s16x8*)F1f)[(et * 2 + 1) * 64 + l];
  }
  f32x4 acc[4];
  #pragma unroll
  for (int et = 0; et < 4; ++et) acc[et] = (f32x4){0.f, 0.f, 0.f, 0.f};

  #pragma unroll
  for (int i = 0; i < 4; ++i){
    const s16x8* p = (const s16x8*)(T1g + (i * 4 + ot) * 1024);
    s16x8 a0 = p[l], a1 = p[64 + l];
    #pragma unroll
    for (int et = 0; et < 4; ++et){
      f32x4 g = (f32x4){0.f, 0.f, 0.f, 0.f};
      g = __builtin_amdgcn_mfma_f32_16x16x32_bf16(a0, bf[et][0], g, 0, 0, 0);
      g = __builtin_amdgcn_mfma_f32_16x16x32_bf16(a1, bf[et][1], g, 0, 0, 0);
      acc[et] += xs[et][i] * g;
    }
  }
  // bias fold: acc[et][r] += sum_i xs[et][i] * e1_b2[i*64 + o],  o = ot*16 + lg*4 + r
  float b2v[4][4];
  #pragma unroll
  for (int i = 0; i < 4; ++i)
    #pragma unroll
    for (int r = 0; r < 4; ++r) b2v[i][r] = e1_b2[i * 64 + ot * 16 + lg * 4 + r];
  #pragma unroll
  for (int et = 0; et < 4; ++et)
    #pragma unroll
    for (int r = 0; r < 4; ++r)
      #pragma unroll
      for (int i = 0; i < 4; ++i) acc[et][r] = fmaf(xs[et][i], b2v[i][r], acc[et][r]);

  #pragma unroll
  for (int et = 0; et < 4; ++et){
    unsigned p0 = ((unsigned)f2bf(acc[et][1]) << 16) | f2bf(acc[et][0]);
    unsigned p1 = ((unsigned)f2bf(acc[et][3]) << 16) | f2bf(acc[et][2]);
    *(uint2*)(msg1b + (size_t)esl[et] * 64 + ot * 16 + lg * 4) = make_uint2(p0, p1);
  }
}

// ---------------- node update 1: CSR gather-mean + root + LN -> h1b (64 nodes/block) ----------------
__launch_bounds__(1024)
__global__ void k_node1(const float* __restrict__ x, const float* __restrict__ root1,
                        const float* __restrict__ bias1, const float* __restrict__ lng,
                        const float* __restrict__ lnb, const int* __restrict__ cnti,
                        const int* __restrict__ lex, const int* __restrict__ bsx,
                        const unsigned short* __restrict__ msg1b, unsigned short* __restrict__ h1b)
{
  const int tid = threadIdx.x;
  const int q = tid >> 6, o = tid & 63;
  #pragma unroll 1
  for (int it = 0; it < 4; ++it){
    int n = blockIdx.x * 64 + it * 16 + q;
    int rp = lex[n] + bsx[n >> 8];
    int deg = cnti[n];
    float s = 0.f;
    for (int j = 0; j < deg; ++j) s += bf2f(msg1b[(size_t)(rp + j) * 64 + o]);
    float v = s * (1.f / fmaxf((float)deg, 1.f));
    float4 xv = *(const float4*)(x + n * 4);
    v = fmaf(xv.x, root1[o], v);
    v = fmaf(xv.y, root1[64 + o], v);
    v = fmaf(xv.z, root1[128 + o], v);
    v = fmaf(xv.w, root1[192 + o], v);
    v = fmaxf(v + bias1[o], 0.f);
    float m = v;
    #pragma unroll
    for (int d = 32; d > 0; d >>= 1) m += __shfl_xor(m, d);
    m *= (1.f / 64.f);
    float dd = v - m;
    float var = dd * dd;
    #pragma unroll
    for (int d = 32; d > 0; d >>= 1) var += __shfl_xor(var, d);
    var *= (1.f / 64.f);
    float out = dd * rsqrtf(var + 1e-5f) * lng[o] + lnb[o];
    h1b[n * 64 + o] = f2bf(out);
  }
}

// ---------------- layer-2 edge messages: 8 waves (ot x eh), f32 F2s, pk-fma scale, asm prefetch ----------------
__launch_bounds__(512, 4)
__global__ void k_msg2(const float* __restrict__ ea, const int* __restrict__ ei,
                       const int* __restrict__ eslot,
                       const float* __restrict__ e2_w1, const float* __restrict__ e2_b1,
                       const unsigned short* __restrict__ h1b,
                       const unsigned short* __restrict__ W2f,
                       float* __restrict__ msg)
{
  __shared__ float eas[128 * 4];
  __shared__ float F2s[128 * 132];   // f32 scales, padded row
  const int tid = threadIdx.x;
  const int eblk = blockIdx.x * 128;
  const int w = tid >> 6, l = tid & 63, lm = l & 15, lg = l >> 4;
  const int ot = w >> 1, eh = w & 1;

  // early scattered loads: issue before the F2 phase so HBM/L2 latency hides under it
  int esl[4];
  s16x8 bh[4][2];
  #pragma unroll
  for (int et = 0; et < 4; ++et){
    int eloc = eh * 64 + et * 16 + lm;
    int e = eblk + eloc;
    int s = ei[e];
    esl[et] = eslot[e];
    const s16x8* hp = (const s16x8*)(h1b + s * 64);
    bh[et][0] = hp[lg];
    bh[et][1] = hp[4 + lg];
  }

  if (tid < 128) ((float4*)eas)[tid] = ((const float4*)ea)[eblk + tid];
  __syncthreads();
  {
    int kf = tid & 127, q = tid >> 7;   // q in 0..3, 32 edges each
    float w0 = e2_w1[kf], w1 = e2_w1[128 + kf], w2 = e2_w1[256 + kf], w3 = e2_w1[384 + kf];
    float bb = e2_b1[kf];
    for (int e = q * 32; e < q * 32 + 32; ++e){
      float s = fmaf(eas[e*4+0], w0, fmaf(eas[e*4+1], w1, fmaf(eas[e*4+2], w2, fmaf(eas[e*4+3], w3, bb))));
      F2s[e * 132 + kf] = fmaxf(s, 0.f);
    }
  }
  __syncthreads();

  f32x2 accL[4], accH[4];
  #pragma unroll
  for (int et = 0; et < 4; ++et){ accL[et] = (f32x2){0.f, 0.f}; accH[et] = (f32x2){0.f, 0.f}; }

  const int voff = ot * 2048 + l * 16;   // byte offset of this lane's fragment within a slab
  s16x8 A0[2], A1[2], A2[2], A3[2];

  // asm loads: compiler cannot sink these to their use; counted vmcnt enforces depth-4 pipeline.
  // NOTE: requires no spilling of A0..A3 (in-flight asm loads) — keep VGPR cap at 128 (512,4).
#define LOADA(DST, KF) { \
    const unsigned short* sb = W2f + (size_t)(KF) * 4096; \
    asm volatile("global_load_dwordx4 %0, %2, %3\n\t" \
                 "global_load_dwordx4 %1, %2, %3 offset:1024" \
      : "=&v"(DST[0]), "=&v"(DST[1]) : "v"(voff), "s"(sb)); }
#define WAITA(N) do { asm volatile("s_waitcnt vmcnt(" #N ")"); \
                      __builtin_amdgcn_sched_barrier(0); } while(0);
#define STEP(A, J) { \
    __builtin_amdgcn_s_setprio(1); \
    _Pragma("unroll") \
    for (int et = 0; et < 4; ++et){ \
      f32x4 g = (f32x4){0.f, 0.f, 0.f, 0.f}; \
      g = __builtin_amdgcn_mfma_f32_16x16x32_bf16(A[0], bh[et][0], g, 0, 0, 0); \
      g = __builtin_amdgcn_mfma_f32_16x16x32_bf16(A[1], bh[et][1], g, 0, 0, 0); \
      float fs = f2c[et][J]; \
      f32x2 ff = (f32x2){fs, fs}; \
      f32x2 glo = __builtin_shufflevector(g, g, 0, 1); \
      f32x2 ghi = __builtin_shufflevector(g, g, 2, 3); \
      accL[et] = __builtin_elementwise_fma(glo, ff, accL[et]); \
      accH[et] = __builtin_elementwise_fma(ghi, ff, accH[et]); \
    } \
    __builtin_amdgcn_s_setprio(0); }

  LOADA(A0, 0)
  LOADA(A1, 1)
  LOADA(A2, 2)
  LOADA(A3, 3)
  #pragma unroll 1
  for (int kf = 0; kf < 128; kf += 4){
    f32x4 f2c[4];
    #pragma unroll
    for (int et = 0; et < 4; ++et)
      f2c[et] = *(const f32x4*)&F2s[(eh * 64 + et * 16 + lm) * 132 + kf];
    const int k5 = (kf + 5 > 128) ? 128 : kf + 5;
    const int k6 = (kf + 6 > 128) ? 128 : kf + 6;
    const int k7 = (kf + 7 > 128) ? 128 : kf + 7;
    WAITA(6) STEP(A0, 0) LOADA(A0, kf + 4)   // kf+4 <= 128 always
    WAITA(6) STEP(A1, 1) LOADA(A1, k5)
    WAITA(6) STEP(A2, 2) LOADA(A2, k6)
    WAITA(6) STEP(A3, 3) LOADA(A3, k7)
  }
  WAITA(0)
  // kf = 128: bias slab (f2 == 1) now in A0, accumulate directly
  #pragma unroll
  for (int et = 0; et < 4; ++et){
    f32x4 g = (f32x4){0.f, 0.f, 0.f, 0.f};
    g = __builtin_amdgcn_mfma_f32_16x16x32_bf16(A0[0], bh[et][0], g, 0, 0, 0);
    g = __builtin_amdgcn_mfma_f32_16x16x32_bf16(A0[1], bh[et][1], g, 0, 0, 0);
    accL[et] += __builtin_shufflevector(g, g, 0, 1);
    accH[et] += __builtin_shufflevector(g, g, 2, 3);
  }
#undef LOADA
#undef WAITA
#undef STEP

  #pragma unroll
  for (int et = 0; et < 4; ++et){
    f32x4 o4;
    o4[0] = accL[et][0]; o4[1] = accL[et][1];
    o4[2] = accH[et][0]; o4[3] = accH[et][1];
    *(f32x4*)(msg + (size_t)esl[et] * 64 + ot * 16 + lg * 4) = o4;
  }
}

// ---------------- node update 2: gather-mean + h1@root2 + LN, 64 nodes/block partials ----------------
__launch_bounds__(1024)
__global__ void k_node2(const unsigned short* __restrict__ h1b, const float* __restrict__ root2,
                        const float* __restrict__ bias2, const float* __restrict__ lng,
                        const float* __restrict__ lnb, const int* __restrict__ cnti,
                        const int* __restrict__ lex, const int* __restrict__ bsx,
                        const float* __restrict__ msg, float* __restrict__ partial)
{
  const int tid = threadIdx.x;
  const int q = tid >> 6, o = tid & 63;
  float tsum = 0.f;
  #pragma unroll 1
  for (int it = 0; it < 4; ++it){
    int n = blockIdx.x * 64 + it * 16 + q;
    int rp = lex[n] + bsx[n >> 8];
    int deg = cnti[n];
    float s = 0.f;
    for (int j = 0; j < deg; ++j) s += msg[(size_t)(rp + j) * 64 + o];
    float v = s * (1.f / fmaxf((float)deg, 1.f));
    const s16x8* hp = (const s16x8*)(h1b + n * 64);
    #pragma unroll
    for (int c = 0; c < 8; ++c){
      s16x8 hv = hp[c];
      #pragma unroll
      for (int j = 0; j < 8; ++j)
        v = fmaf(bf2f((unsigned short)hv[j]), root2[(c * 8 + j) * 64 + o], v);
    }
    v = fmaxf(v + bias2[o], 0.f);
    float m = v;
    #pragma unroll
    for (int d = 32; d > 0; d >>= 1) m += __shfl_xor(m, d);
    m *= (1.f / 64.f);
    float dd = v - m;
    float var = dd * dd;
    #pragma unroll
    for (int d = 32; d > 0; d >>= 1) var += __shfl_xor(var, d);
    var *= (1.f / 64.f);
    tsum += dd * rsqrtf(var + 1e-5f) * lng[o] + lnb[o];
  }
  __shared__ float pp[16][64];
  pp[q][o] = tsum;
  __syncthreads();
  if (tid < 64){
    float t = 0.f;
    #pragma unroll
    for (int k = 0; k < 16; ++k) t += pp[k][tid];
    partial[blockIdx.x * 64 + tid] = t;
  }
}

// ---------------- final reduce: 512 partial rows -> 64 outputs ----------------
__launch_bounds__(1024)
__global__ void k_out(const float* __restrict__ partial, float* __restrict__ out){
  const int tid = threadIdx.x;
  int o = tid & 63, q = tid >> 6;      // q in 0..15
  float s = 0.f;
  for (int b = q; b < 512; b += 16) s += partial[b * 64 + o];
  __shared__ float pp[16][64];
  pp[q][o] = s;
  __syncthreads();
  if (tid < 64){
    float t = 0.f;
    #pragma unroll
    for (int k = 0; k < 16; ++k) t += pp[k][tid];
    out[tid] = t * (1.f / 32768.f);
  }
}

extern "C" void kernel_launch(void* const* d_in, const int* in_sizes, int n_in,
                              void* d_out, int out_size, void* d_ws, size_t ws_size,
                              hipStream_t stream)
{
  const float* x      = (const float*)d_in[0];
  const float* ea     = (const float*)d_in[1];
  const int*   ei     = (const int*)  d_in[2];
  const float* e1_w1  = (const float*)d_in[4];
  const float* e1_b1  = (const float*)d_in[5];
  const float* e1_w2  = (const float*)d_in[6];
  const float* e1_b2  = (const float*)d_in[7];
  const float* root1  = (const float*)d_in[8];
  const float* bias1  = (const float*)d_in[9];
  const float* ln1g   = (const float*)d_in[10];
  const float* ln1b   = (const float*)d_in[11];
  const float* e2_w1  = (const float*)d_in[12];
  const float* e2_b1  = (const float*)d_in[13];
  const float* e2_w2  = (const float*)d_in[14];
  const float* e2_b2  = (const float*)d_in[15];
  const float* root2  = (const float*)d_in[16];
  const float* bias2  = (const float*)d_in[17];
  const float* ln2g   = (const float*)d_in[18];
  const float* ln2b   = (const float*)d_in[19];

  char* w = (char*)d_ws;
  float*          msg     = (float*)(w);                       // 16,777,216 B (f32, layer 2)
  unsigned short* msg1b   = (unsigned short*)(w);              //  8,388,608 B (bf16, layer 1 — overlaid)
  unsigned short* h1b     = (unsigned short*)(w + 16777216);   //  4,194,304 B
  unsigned short* W2f     = (unsigned short*)(w + 20971520);   //  1,056,768 B
  unsigned short* T1g     = (unsigned short*)(w + 22028288);   //     32,768 B
  int*            cnti    = (int*)(w + 22061056);              //    131,072 B  (zeroed in k_prep)
  int*            cur     = (int*)(w + 22192128);              //    131,072 B  (zeroed in k_prep)
  int*            lex     = (int*)(w + 22323200);              //    131,072 B
  int*            bsx     = (int*)(w + 22454272);              //        512 B
  int*            bsum    = (int*)(w + 22454784);              //        512 B
  int*            eslot   = (int*)(w + 22455296);              //    262,144 B
  float*          partial = (float*)(w + 22717440);            //    131,072 B

  k_prep <<<449, 256, 0, stream>>>(e2_w2, e2_b2, e1_w2, W2f, T1g, cnti);
  k_hist <<<256, 256, 0, stream>>>(ei, cnti);
  k_scanA<<<128, 256, 0, stream>>>(cnti, lex, bsum);
  k_fill <<<256, 256, 0, stream>>>(ei, lex, bsum, cur, eslot, bsx);
  k_msg1 <<<1024, 256, 0, stream>>>(x, ea, ei, eslot, e1_w1, e1_b1, e1_b2, T1g, msg1b);
  k_node1<<<512, 1024, 0, stream>>>(x, root1, bias1, ln1g, ln1b, cnti, lex, bsx, msg1b, h1b);
  k_msg2 <<<512, 512, 0, stream>>>(ea, ei, eslot, e2_w1, e2_b1, h1b, W2f, msg);
  k_node2<<<512, 1024, 0, stream>>>(h1b, root2, bias2, ln2g, ln2b, cnti, lex, bsx, msg, partial);
  k_out  <<<1, 1024, 0, stream>>>(partial, (float*)d_out);
}